// Round 1
// baseline (2298.546 us; speedup 1.0000x reference)
//
#include <hip/hip_runtime.h>
#include <stdint.h>
#include <stddef.h>

typedef _Float16 f16;
typedef _Float16 f16x8 __attribute__((ext_vector_type(8)));
typedef float floatx4 __attribute__((ext_vector_type(4)));

#define BN_EPS 1e-5f

// ---------------------------------------------------------------------------
// conversion kernels
// ---------------------------------------------------------------------------

// fp32 [n,c] -> fp16 into dst[r*ldd + coff + j]  (c % 4 == 0)
__global__ void k_cvt_cols(const float* __restrict__ src, f16* __restrict__ dst,
                           int n, int c, int ldd, int coff) {
  int t = blockIdx.x * blockDim.x + threadIdx.x;
  int cq = c >> 2;
  if (t >= n * cq) return;
  int r = t / cq, j = (t - r * cq) << 2;
  float4 v = *(const float4*)(src + (size_t)r * c + j);
  f16* p = dst + (size_t)r * ldd + coff + j;
  p[0] = (f16)v.x; p[1] = (f16)v.y; p[2] = (f16)v.z; p[3] = (f16)v.w;
}

// W [K,N] fp32 -> Wt [N,K] fp16 (transpose-convert; weights are tiny)
__global__ void k_wt(const float* __restrict__ W, f16* __restrict__ Wt, int K, int N) {
  int t = blockIdx.x * blockDim.x + threadIdx.x;
  if (t >= K * N) return;
  int k = t / N, n = t - k * N;
  Wt[(size_t)n * K + k] = (f16)W[t];
}

// ---------------------------------------------------------------------------
// CSR build: count -> scan(+deg->dis) -> fill
// ---------------------------------------------------------------------------

__global__ void k_count(const int* __restrict__ dst, int E, int* __restrict__ cnt) {
  int t = blockIdx.x * blockDim.x + threadIdx.x;
  if (t < E) atomicAdd(&cnt[dst[t]], 1);
}

// single block, 1024 threads: rowstart = exclusive scan of cnt; dis = rsqrt(1+cnt)
__global__ void k_scan(const int* __restrict__ cnt, int n, int* __restrict__ rowstart,
                       float* __restrict__ dis) {
  __shared__ int wsum[16];
  __shared__ int carry_s;
  int tid = threadIdx.x, lane = tid & 63, wv = tid >> 6;
  if (tid == 0) { carry_s = 0; rowstart[0] = 0; }
  __syncthreads();
  for (int base = 0; base < n; base += 1024) {
    int i = base + tid;
    int x = (i < n) ? cnt[i] : 0;
    int orig = x;
    #pragma unroll
    for (int off = 1; off < 64; off <<= 1) {
      int y = __shfl_up(x, off, 64);
      if (lane >= off) x += y;
    }
    if (lane == 63) wsum[wv] = x;
    __syncthreads();
    if (wv == 0) {
      int s = (lane < 16) ? wsum[lane] : 0;
      #pragma unroll
      for (int off = 1; off < 16; off <<= 1) {
        int y = __shfl_up(s, off, 64);
        if (lane >= off) s += y;
      }
      if (lane < 16) wsum[lane] = s;
    }
    __syncthreads();
    int waveoff = (wv == 0) ? 0 : wsum[wv - 1];
    int incl = x + waveoff + carry_s;
    if (i < n) {
      rowstart[i + 1] = incl;
      dis[i] = rsqrtf(1.0f + (float)orig);
    }
    __syncthreads();
    if (tid == 1023) carry_s = incl;
    __syncthreads();
  }
}

__global__ void k_fill(const int* __restrict__ ei, int E, const int* __restrict__ rowstart,
                       int* __restrict__ fill, int* __restrict__ colidx) {
  int t = blockIdx.x * blockDim.x + threadIdx.x;
  if (t >= E) return;
  int s = ei[t], d = ei[E + t];
  int pos = atomicAdd(&fill[d], 1);
  colidx[rowstart[d] + pos] = s;
}

// ---------------------------------------------------------------------------
// GCN aggregation (gather over CSR) + self term + bias -> vbuf (fp32)
// one block per destination node; threads over channels (coalesced)
// ---------------------------------------------------------------------------
__global__ void k_gather(const f16* __restrict__ xw, int C,
                         const int* __restrict__ rowstart, const int* __restrict__ colidx,
                         const float* __restrict__ dis, const float* __restrict__ bias,
                         float* __restrict__ vbuf) {
  int j = blockIdx.x;
  float dj = dis[j];
  int rs = rowstart[j], re = rowstart[j + 1];
  for (int c = threadIdx.x; c < C; c += blockDim.x) {
    float acc = (float)xw[(size_t)j * C + c] * (dj * dj);  // self: xw[j]/deg_j
    for (int e = rs; e < re; ++e) {
      int s = colidx[e];
      acc += (float)xw[(size_t)s * C + c] * (dis[s] * dj);
    }
    vbuf[(size_t)j * C + c] = acc + bias[c];
  }
}

// ---------------------------------------------------------------------------
// BatchNorm: column stats -> params -> apply(+relu) into fp16 cat slice
// ---------------------------------------------------------------------------
__global__ void k_stats(const float* __restrict__ v, int n, int C,
                        float* __restrict__ sum, float* __restrict__ sumsq) {
  int c = blockIdx.x * blockDim.x + threadIdx.x;
  if (c >= C) return;
  int r0 = blockIdx.y * 128, r1 = min(r0 + 128, n);
  float s = 0.f, s2 = 0.f;
  for (int r = r0; r < r1; ++r) {
    float x = v[(size_t)r * C + c];
    s += x; s2 += x * x;
  }
  atomicAdd(&sum[c], s);
  atomicAdd(&sumsq[c], s2);
}

__global__ void k_bnparam(const float* __restrict__ sum, const float* __restrict__ sumsq,
                          const float* __restrict__ gamma, const float* __restrict__ beta,
                          int n, int C, float* __restrict__ scale, float* __restrict__ shift) {
  int c = blockIdx.x * blockDim.x + threadIdx.x;
  if (c >= C) return;
  float mean = sum[c] / (float)n;
  float var = sumsq[c] / (float)n - mean * mean;
  float sc = gamma[c] * rsqrtf(var + BN_EPS);
  scale[c] = sc;
  shift[c] = beta[c] - mean * sc;
}

__global__ void k_bnapply(const float* __restrict__ v, int n, int C,
                          const float* __restrict__ scale, const float* __restrict__ shift,
                          f16* __restrict__ dst, int ldd, int coff) {
  int t = blockIdx.x * blockDim.x + threadIdx.x;
  if (t >= n * C) return;
  int r = t / C, c = t - r * C;
  float h = fmaxf(v[t] * scale[c] + shift[c], 0.f);
  dst[(size_t)r * ldd + coff + c] = (f16)h;
}

// ---------------------------------------------------------------------------
// fp16 MFMA GEMM: C[M,N] = A[M,K] @ Bt[N,K]^T  (+bias, +relu), fp16 out
// 128x128 tile, 4 waves (2x2 of 64x64), 16x16x32 f16 MFMA, BK=32
// global_load_lds width=16 staging, XOR chunk swizzle (2-way bank alias = free)
// ---------------------------------------------------------------------------
__global__ __launch_bounds__(256)
void k_gemm(const f16* __restrict__ A, int lda,
            const f16* __restrict__ Bt,
            f16* __restrict__ C, int ldc,
            const float* __restrict__ bias, int relu,
            int M, int N, int K) {
  __shared__ f16 Ash[128 * 32];
  __shared__ f16 Bsh[128 * 32];
  int tid = threadIdx.x;
  int l = tid & 63, w = tid >> 6;
  int tm = blockIdx.y * 128, tn = blockIdx.x * 128;

  // staging: each wave issues 2 A-loads + 2 B-loads per K-iter (16 rows x 64B each)
  const f16* ag[2]; const f16* bg[2];
  uint32_t lof[2];
  #pragma unroll
  for (int j = 0; j < 2; ++j) {
    int rl = w * 32 + j * 16 + (l >> 2);      // local row / local col
    int ck = l & 3;                           // physical 16B chunk slot
    int lc = ck ^ ((rl >> 1) & 3);            // logical chunk fetched (XOR swizzle)
    int gr = tm + rl; if (gr > M - 1) gr = M - 1;
    int gn = tn + rl; if (gn > N - 1) gn = N - 1;
    ag[j] = A + (size_t)gr * lda + lc * 8;
    bg[j] = Bt + (size_t)gn * K + lc * 8;
    lof[j] = (uint32_t)(w * 32 + j * 16) * 64; // wave-uniform LDS byte base
  }

  // fragment LDS pointers (loop-invariant)
  int wm = (w >> 1) * 64, wn = (w & 1) * 64;
  int q = l >> 4, l15 = l & 15;
  const f16x8* apf[4]; const f16x8* bpf[4];
  #pragma unroll
  for (int i = 0; i < 4; ++i) {
    int m = wm + i * 16 + l15;
    apf[i] = (const f16x8*)&Ash[m * 32 + (q ^ ((m >> 1) & 3)) * 8];
    int n2 = wn + i * 16 + l15;
    bpf[i] = (const f16x8*)&Bsh[n2 * 32 + (q ^ ((n2 >> 1) & 3)) * 8];
  }

  floatx4 acc[4][4];
  #pragma unroll
  for (int i = 0; i < 4; ++i)
    #pragma unroll
    for (int j = 0; j < 4; ++j) acc[i][j] = (floatx4){0.f, 0.f, 0.f, 0.f};

  for (int k0 = 0; k0 < K; k0 += 32) {
    if (k0) __syncthreads();
    #pragma unroll
    for (int j = 0; j < 2; ++j) {
      __builtin_amdgcn_global_load_lds(
          (const __attribute__((address_space(1))) void*)ag[j],
          (__attribute__((address_space(3))) void*)((char*)Ash + lof[j]), 16, 0, 0);
      __builtin_amdgcn_global_load_lds(
          (const __attribute__((address_space(1))) void*)bg[j],
          (__attribute__((address_space(3))) void*)((char*)Bsh + lof[j]), 16, 0, 0);
      ag[j] += 32; bg[j] += 32;
    }
    __syncthreads();  // drains vmcnt(0) for the LDS-DMA
    f16x8 af[4], bf[4];
    #pragma unroll
    for (int i = 0; i < 4; ++i) { af[i] = *apf[i]; bf[i] = *bpf[i]; }
    #pragma unroll
    for (int mi = 0; mi < 4; ++mi)
      #pragma unroll
      for (int ni = 0; ni < 4; ++ni)
        acc[mi][ni] = __builtin_amdgcn_mfma_f32_16x16x32_f16(af[mi], bf[ni], acc[mi][ni], 0, 0, 0);
  }

  // epilogue: C/D layout col=lane&15, row=quad*4+reg (m89-verified)
  #pragma unroll
  for (int ni = 0; ni < 4; ++ni) {
    int col = tn + wn + ni * 16 + l15;
    if (col >= N) continue;
    float b = bias ? bias[col] : 0.f;
    #pragma unroll
    for (int mi = 0; mi < 4; ++mi) {
      int rowb = tm + wm + mi * 16 + q * 4;
      #pragma unroll
      for (int r = 0; r < 4; ++r) {
        int row = rowb + r;
        if (row < M) {
          float v = acc[mi][ni][r] + b;
          if (relu) v = fmaxf(v, 0.f);
          C[(size_t)row * ldc + col] = (f16)v;
        }
      }
    }
  }
}

// ---------------------------------------------------------------------------
// small-N final FC: out[M,NOUT] = A[M,K](fp16) @ W[K,NOUT](fp32) + b, fp32 out
// one wave per row; W staged in LDS
// ---------------------------------------------------------------------------
template <int NOUT>
__global__ void k_smallfc(const f16* __restrict__ A, int lda, int M, int K,
                          const float* __restrict__ W, const float* __restrict__ b,
                          float* __restrict__ out) {
  extern __shared__ float Wl[];
  int tid = threadIdx.x;
  for (int i = tid; i < K * NOUT; i += blockDim.x) Wl[i] = W[i];
  __syncthreads();
  int wv = tid >> 6, lane = tid & 63;
  int row = blockIdx.x * 4 + wv;
  if (row >= M) return;
  float acc[NOUT];
  #pragma unroll
  for (int n = 0; n < NOUT; ++n) acc[n] = 0.f;
  for (int k = lane; k < K; k += 64) {
    float a = (float)A[(size_t)row * lda + k];
    #pragma unroll
    for (int n = 0; n < NOUT; ++n) acc[n] += a * Wl[k * NOUT + n];
  }
  #pragma unroll
  for (int n = 0; n < NOUT; ++n)
    #pragma unroll
    for (int off = 32; off > 0; off >>= 1) acc[n] += __shfl_down(acc[n], off, 64);
  if (lane == 0) {
    #pragma unroll
    for (int n = 0; n < NOUT; ++n) out[(size_t)row * NOUT + n] = acc[n] + b[n];
  }
}

// ---------------------------------------------------------------------------
// host orchestration
// ---------------------------------------------------------------------------
extern "C" void kernel_launch(void* const* d_in, const int* in_sizes, int n_in,
                              void* d_out, int out_size, void* d_ws, size_t ws_size,
                              hipStream_t stream) {
  (void)in_sizes; (void)n_in; (void)out_size; (void)ws_size;
  const int NL = 50000, NJ = 25000, EL = 400000, EJ = 100000;

  const float* x_l  = (const float*)d_in[0];
  const float* x_j  = (const float*)d_in[1];
  const int*   ei_l = (const int*)d_in[2];
  const int*   ei_j = (const int*)d_in[3];
  const float* lgW1 = (const float*)d_in[4];  const float* lgb1 = (const float*)d_in[5];
  const float* lgg1 = (const float*)d_in[6];  const float* lgbe1= (const float*)d_in[7];
  const float* lgW2 = (const float*)d_in[8];  const float* lgb2 = (const float*)d_in[9];
  const float* lgg2 = (const float*)d_in[10]; const float* lgbe2= (const float*)d_in[11];
  const float* lgfcW= (const float*)d_in[12]; const float* lgfcb= (const float*)d_in[13];
  const float* flW1 = (const float*)d_in[14]; const float* flb1 = (const float*)d_in[15];
  const float* flW2 = (const float*)d_in[16]; const float* flb2 = (const float*)d_in[17];
  const float* flW3 = (const float*)d_in[18]; const float* flb3 = (const float*)d_in[19];
  const float* jgW1 = (const float*)d_in[20]; const float* jgb1 = (const float*)d_in[21];
  const float* jgg1 = (const float*)d_in[22]; const float* jgbe1= (const float*)d_in[23];
  const float* jgW2 = (const float*)d_in[24]; const float* jgb2 = (const float*)d_in[25];
  const float* jgg2 = (const float*)d_in[26]; const float* jgbe2= (const float*)d_in[27];
  const float* jgfcW= (const float*)d_in[28]; const float* jgfcb= (const float*)d_in[29];
  const float* fjW1 = (const float*)d_in[30]; const float* fjb1 = (const float*)d_in[31];
  const float* fjW2 = (const float*)d_in[32]; const float* fjb2 = (const float*)d_in[33];

  char* ws = (char*)d_ws;
  size_t off = 0;
  auto alloc = [&](size_t bytes) -> char* {
    char* p = ws + off;
    off += (bytes + 255) & ~(size_t)255;
    return p;
  };

  f16* cat16 = (f16*)alloc((size_t)NL * 1792 * 2);   // [x | h1 | h2]
  f16* hA    = (f16*)alloc((size_t)NL * 1024 * 2);
  f16* hB    = (f16*)alloc((size_t)NL * 1024 * 2);
  float* vbuf = (float*)hA;   // alias: GCN phase only (hA first written at fc)
  f16*  xw16  = (f16*)hB;     // alias: GCN phase only (hB first written at fl1)
  f16* catJ  = (f16*)alloc((size_t)NJ * 448 * 2);
  f16* hJA   = (f16*)alloc((size_t)NJ * 256 * 2);
  f16* hJB   = (f16*)alloc((size_t)NJ * 64 * 2);
  float* vbufJ = (float*)hA;  // junction branch runs after line branch completes
  f16*  xwJ   = (f16*)hB;

  f16* W1t   = (f16*)alloc((size_t)1024 * 512 * 2);
  f16* W2t   = (f16*)alloc((size_t)512 * 256 * 2);
  f16* fcWt  = (f16*)alloc((size_t)1792 * 1024 * 2);
  f16* flW1t = (f16*)alloc((size_t)1024 * 1024 * 2);
  f16* flW2t = (f16*)alloc((size_t)1024 * 1024 * 2);
  f16* jW1t  = (f16*)alloc((size_t)256 * 128 * 2);
  f16* jW2t  = (f16*)alloc((size_t)128 * 64 * 2);
  f16* jfcWt = (f16*)alloc((size_t)448 * 256 * 2);
  f16* fjW1t = (f16*)alloc((size_t)256 * 64 * 2);

  int* cntL  = (int*)alloc((size_t)NL * 4);
  int* rsL   = (int*)alloc((size_t)(NL + 1) * 4);
  int* fillL = (int*)alloc((size_t)NL * 4);
  int* cixL  = (int*)alloc((size_t)EL * 4);
  float* disL= (float*)alloc((size_t)NL * 4);
  int* cntJ  = (int*)alloc((size_t)NJ * 4);
  int* rsJ   = (int*)alloc((size_t)(NJ + 1) * 4);
  int* fillJ = (int*)alloc((size_t)NJ * 4);
  int* cixJ  = (int*)alloc((size_t)EJ * 4);
  float* disJ= (float*)alloc((size_t)NJ * 4);
  float* sumc  = (float*)alloc(512 * 4);
  float* sumqc = (float*)alloc(512 * 4);
  float* scalc = (float*)alloc(512 * 4);
  float* shftc = (float*)alloc(512 * 4);

  auto cdiv = [](int a, int b) { return (a + b - 1) / b; };

  auto wt = [&](const float* W, f16* Wt, int K, int N) {
    k_wt<<<cdiv(K * N, 256), 256, 0, stream>>>(W, Wt, K, N);
  };
  auto gemm = [&](const f16* A, int lda, const f16* Bt, f16* Cc, int ldc,
                  const float* bias, int relu, int M, int N, int K) {
    dim3 g(cdiv(N, 128), cdiv(M, 128));
    k_gemm<<<g, 256, 0, stream>>>(A, lda, Bt, Cc, ldc, bias, relu, M, N, K);
  };
  auto csr = [&](const int* ei, int E, int n, int* cnt, int* rs, int* fill,
                 int* cix, float* dis) {
    hipMemsetAsync(cnt, 0, (size_t)n * 4, stream);
    k_count<<<cdiv(E, 256), 256, 0, stream>>>(ei + E, E, cnt);
    k_scan<<<1, 1024, 0, stream>>>(cnt, n, rs, dis);
    hipMemsetAsync(fill, 0, (size_t)n * 4, stream);
    k_fill<<<cdiv(E, 256), 256, 0, stream>>>(ei, E, rs, fill, cix);
  };
  auto bn = [&](float* v, int n, int C, const float* gamma, const float* beta,
                f16* dst, int ldd, int coff) {
    hipMemsetAsync(sumc, 0, (size_t)C * 4, stream);
    hipMemsetAsync(sumqc, 0, (size_t)C * 4, stream);
    dim3 gs(cdiv(C, 256), cdiv(n, 128));
    k_stats<<<gs, 256, 0, stream>>>(v, n, C, sumc, sumqc);
    k_bnparam<<<cdiv(C, 256), 256, 0, stream>>>(sumc, sumqc, gamma, beta, n, C, scalc, shftc);
    k_bnapply<<<cdiv(n * C, 256), 256, 0, stream>>>(v, n, C, scalc, shftc, dst, ldd, coff);
  };

  // ---- weight conversion (re-done every call: d_ws is re-poisoned) ----
  wt(lgW1, W1t, 1024, 512);
  wt(lgW2, W2t, 512, 256);
  wt(lgfcW, fcWt, 1792, 1024);
  wt(flW1, flW1t, 1024, 1024);
  wt(flW2, flW2t, 1024, 1024);
  wt(jgW1, jW1t, 256, 128);
  wt(jgW2, jW2t, 128, 64);
  wt(jgfcW, jfcWt, 448, 256);
  wt(fjW1, fjW1t, 256, 64);

  // ---- feature conversion into concat buffers ----
  k_cvt_cols<<<cdiv(NL * 256, 256), 256, 0, stream>>>(x_l, cat16, NL, 1024, 1792, 0);
  k_cvt_cols<<<cdiv(NJ * 64, 256), 256, 0, stream>>>(x_j, catJ, NJ, 256, 448, 0);

  // ================= line branch =================
  csr(ei_l, EL, NL, cntL, rsL, fillL, cixL, disL);

  // GCN layer 1: 1024 -> 512
  gemm(cat16, 1792, W1t, xw16, 512, nullptr, 0, NL, 512, 1024);
  k_gather<<<NL, 256, 0, stream>>>(xw16, 512, rsL, cixL, disL, lgb1, vbuf);
  bn(vbuf, NL, 512, lgg1, lgbe1, cat16, 1792, 1024);

  // GCN layer 2: 512 -> 256
  gemm(cat16 + 1024, 1792, W2t, xw16, 256, nullptr, 0, NL, 256, 512);
  k_gather<<<NL, 256, 0, stream>>>(xw16, 256, rsL, cixL, disL, lgb2, vbuf);
  bn(vbuf, NL, 256, lgg2, lgbe2, cat16, 1792, 1536);

  // fc over concat(1792) + fl stack
  gemm(cat16, 1792, fcWt, hA, 1024, lgfcb, 1, NL, 1024, 1792);
  gemm(hA, 1024, flW1t, hB, 1024, flb1, 1, NL, 1024, 1024);
  gemm(hB, 1024, flW2t, hA, 1024, flb2, 1, NL, 1024, 1024);
  k_smallfc<10><<<cdiv(NL, 4), 256, 1024 * 10 * 4, stream>>>(
      hA, 1024, NL, 1024, flW3, flb3, (float*)d_out);

  // ================= junction branch (after line: reuses hA/hB aliases) =====
  csr(ei_j, EJ, NJ, cntJ, rsJ, fillJ, cixJ, disJ);

  gemm(catJ, 448, jW1t, xwJ, 128, nullptr, 0, NJ, 128, 256);
  k_gather<<<NJ, 256, 0, stream>>>(xwJ, 128, rsJ, cixJ, disJ, jgb1, vbufJ);
  bn(vbufJ, NJ, 128, jgg1, jgbe1, catJ, 448, 256);

  gemm(catJ + 256, 448, jW2t, xwJ, 64, nullptr, 0, NJ, 64, 128);
  k_gather<<<NJ, 256, 0, stream>>>(xwJ, 64, rsJ, cixJ, disJ, jgb2, vbufJ);
  bn(vbufJ, NJ, 64, jgg2, jgbe2, catJ, 448, 384);

  gemm(catJ, 448, jfcWt, hJA, 256, jgfcb, 1, NJ, 256, 448);
  gemm(hJA, 256, fjW1t, hJB, 64, fjb1, 1, NJ, 64, 256);
  k_smallfc<3><<<cdiv(NJ, 4), 256, 64 * 3 * 4, stream>>>(
      hJB, 64, NJ, 64, fjW2, fjb2, (float*)d_out + (size_t)NL * 10);
}

// Round 2
// 1748.703 us; speedup vs baseline: 1.3144x; 1.3144x over previous
//
#include <hip/hip_runtime.h>
#include <stdint.h>
#include <stddef.h>

typedef _Float16 f16;
typedef _Float16 f16x8 __attribute__((ext_vector_type(8)));
typedef _Float16 f16x4_t __attribute__((ext_vector_type(4)));
typedef float floatx4 __attribute__((ext_vector_type(4)));

template <int N> struct F16Vec { typedef f16 type __attribute__((ext_vector_type(N))); };

#define BN_EPS 1e-5f

// ---------------------------------------------------------------------------
// fused weight transpose-convert: W [K,N] fp32 -> Wt [N,K] fp16, many at once
// ---------------------------------------------------------------------------
struct WtJob { const float* W; f16* Wt; int K; int N; int base; };
struct WtBatch { WtJob j[12]; int njobs; int total; };

__global__ void k_wt_all(WtBatch b) {
  int t = blockIdx.x * blockDim.x + threadIdx.x;
  if (t >= b.total) return;
  int i = 0;
  #pragma unroll 1
  while (i + 1 < b.njobs && t >= b.j[i + 1].base) ++i;
  WtJob J = b.j[i];
  int r = t - J.base;
  int k = r / J.N, n = r - k * J.N;
  J.Wt[(size_t)n * J.K + k] = (f16)J.W[r];
}

// fp32 [n,c] -> fp16 into dst[r*ldd + coff + j]  (c % 4 == 0)
__global__ void k_cvt_cols(const float* __restrict__ src, f16* __restrict__ dst,
                           int n, int c, int ldd, int coff) {
  int t = blockIdx.x * blockDim.x + threadIdx.x;
  int cq = c >> 2;
  if (t >= n * cq) return;
  int r = t / cq, j = (t - r * cq) << 2;
  float4 v = *(const float4*)(src + (size_t)r * c + j);
  f16x4_t o; o[0] = (f16)v.x; o[1] = (f16)v.y; o[2] = (f16)v.z; o[3] = (f16)v.w;
  *(f16x4_t*)(dst + (size_t)r * ldd + coff + j) = o;
}

// ---------------------------------------------------------------------------
// CSR build: count -> scan(+deg->dis) -> fill
// ---------------------------------------------------------------------------
__global__ void k_count(const int* __restrict__ dst, int E, int* __restrict__ cnt) {
  int t = blockIdx.x * blockDim.x + threadIdx.x;
  if (t < E) atomicAdd(&cnt[dst[t]], 1);
}

__global__ void k_scan(const int* __restrict__ cnt, int n, int* __restrict__ rowstart,
                       float* __restrict__ dis) {
  __shared__ int wsum[16];
  __shared__ int carry_s;
  int tid = threadIdx.x, lane = tid & 63, wv = tid >> 6;
  if (tid == 0) { carry_s = 0; rowstart[0] = 0; }
  __syncthreads();
  for (int base = 0; base < n; base += 1024) {
    int i = base + tid;
    int x = (i < n) ? cnt[i] : 0;
    int orig = x;
    #pragma unroll
    for (int off = 1; off < 64; off <<= 1) {
      int y = __shfl_up(x, off, 64);
      if (lane >= off) x += y;
    }
    if (lane == 63) wsum[wv] = x;
    __syncthreads();
    if (wv == 0) {
      int s = (lane < 16) ? wsum[lane] : 0;
      #pragma unroll
      for (int off = 1; off < 16; off <<= 1) {
        int y = __shfl_up(s, off, 64);
        if (lane >= off) s += y;
      }
      if (lane < 16) wsum[lane] = s;
    }
    __syncthreads();
    int waveoff = (wv == 0) ? 0 : wsum[wv - 1];
    int incl = x + waveoff + carry_s;
    if (i < n) {
      rowstart[i + 1] = incl;
      dis[i] = rsqrtf(1.0f + (float)orig);
    }
    __syncthreads();
    if (tid == 1023) carry_s = incl;
    __syncthreads();
  }
}

__global__ void k_fill(const int* __restrict__ ei, int E, const int* __restrict__ rowstart,
                       int* __restrict__ fill, int* __restrict__ colidx) {
  int t = blockIdx.x * blockDim.x + threadIdx.x;
  if (t >= E) return;
  int s = ei[t], d = ei[E + t];
  int pos = atomicAdd(&fill[d], 1);
  colidx[rowstart[d] + pos] = s;
}

// ---------------------------------------------------------------------------
// GCN aggregation: one WAVE per node, CPL channels per lane (vector loads),
// 2-edge unroll for load ILP. acc fp32. adds self term + bias.
// ---------------------------------------------------------------------------
template <int CPL>
__global__ void k_gather_v(const f16* __restrict__ xw, int C,
                           const int* __restrict__ rowstart, const int* __restrict__ colidx,
                           const float* __restrict__ dis, const float* __restrict__ bias,
                           float* __restrict__ vbuf, int n) {
  typedef typename F16Vec<CPL>::type V;
  int w = threadIdx.x >> 6, l = threadIdx.x & 63;
  int j = blockIdx.x * 4 + w;
  if (j >= n) return;
  float dj = dis[j];
  int rs = rowstart[j], re = rowstart[j + 1];
  int c0 = l * CPL;
  float acc[CPL];
  {
    V p = *(const V*)(xw + (size_t)j * C + c0);
    float s = dj * dj;
    #pragma unroll
    for (int t = 0; t < CPL; ++t) acc[t] = (float)p[t] * s;
  }
  int e = rs;
  for (; e + 2 <= re; e += 2) {
    int s0 = colidx[e], s1 = colidx[e + 1];
    float f0 = dis[s0] * dj, f1 = dis[s1] * dj;
    V p0 = *(const V*)(xw + (size_t)s0 * C + c0);
    V p1 = *(const V*)(xw + (size_t)s1 * C + c0);
    #pragma unroll
    for (int t = 0; t < CPL; ++t) acc[t] += (float)p0[t] * f0 + (float)p1[t] * f1;
  }
  if (e < re) {
    int s0 = colidx[e];
    float f0 = dis[s0] * dj;
    V p0 = *(const V*)(xw + (size_t)s0 * C + c0);
    #pragma unroll
    for (int t = 0; t < CPL; ++t) acc[t] += (float)p0[t] * f0;
  }
  float* o = vbuf + (size_t)j * C + c0;
  #pragma unroll
  for (int t = 0; t < CPL; ++t) o[t] = acc[t] + bias[c0 + t];
}

// ---------------------------------------------------------------------------
// BatchNorm: column stats -> params -> apply(+relu) into fp16 cat slice
// ---------------------------------------------------------------------------
__global__ void k_stats(const float* __restrict__ v, int n, int C,
                        float* __restrict__ sum, float* __restrict__ sumsq) {
  int c = blockIdx.x * blockDim.x + threadIdx.x;
  if (c >= C) return;
  int r0 = blockIdx.y * 128, r1 = min(r0 + 128, n);
  float s = 0.f, s2 = 0.f;
  for (int r = r0; r < r1; ++r) {
    float x = v[(size_t)r * C + c];
    s += x; s2 += x * x;
  }
  atomicAdd(&sum[c], s);
  atomicAdd(&sumsq[c], s2);
}

__global__ void k_bnparam(const float* __restrict__ sum, const float* __restrict__ sumsq,
                          const float* __restrict__ gamma, const float* __restrict__ beta,
                          int n, int C, float* __restrict__ scale, float* __restrict__ shift) {
  int c = blockIdx.x * blockDim.x + threadIdx.x;
  if (c >= C) return;
  float mean = sum[c] / (float)n;
  float var = sumsq[c] / (float)n - mean * mean;
  float sc = gamma[c] * rsqrtf(var + BN_EPS);
  scale[c] = sc;
  shift[c] = beta[c] - mean * sc;
}

__global__ void k_bnapply(const float* __restrict__ v, int n, int C,
                          const float* __restrict__ scale, const float* __restrict__ shift,
                          f16* __restrict__ dst, int ldd, int coff) {
  int t = blockIdx.x * blockDim.x + threadIdx.x;
  int cq = C >> 2;
  if (t >= n * cq) return;
  int r = t / cq, c = (t - r * cq) << 2;
  float4 x = *(const float4*)(v + (size_t)r * C + c);
  float4 sc = *(const float4*)(scale + c);
  float4 sh = *(const float4*)(shift + c);
  f16x4_t o;
  o[0] = (f16)fmaxf(x.x * sc.x + sh.x, 0.f);
  o[1] = (f16)fmaxf(x.y * sc.y + sh.y, 0.f);
  o[2] = (f16)fmaxf(x.z * sc.z + sh.z, 0.f);
  o[3] = (f16)fmaxf(x.w * sc.w + sh.w, 0.f);
  *(f16x4_t*)(dst + (size_t)r * ldd + coff + c) = o;
}

// ---------------------------------------------------------------------------
// fp16 MFMA GEMM: C[M,N] = A[M,K] @ Bt[N,K]^T  (+bias, +relu), f16 or f32 out
// 128x128 tile, 4 waves (2x2 of 64x64), 16x16x32 f16 MFMA, BK=64.
// global_load_lds width=16 staging, 8-chunk XOR swizzle (2-way alias = free),
// XCD-aware 1D block swizzle: xcd = b&7 owns contiguous run of row-major tiles.
// ---------------------------------------------------------------------------
__global__ __launch_bounds__(256)
void k_gemm(const f16* __restrict__ A, int lda,
            const f16* __restrict__ Bt,
            void* __restrict__ Cv, int ldc,
            const float* __restrict__ bias, int relu, int outf,
            int M, int N, int K, int mt, int nt, int per) {
  __shared__ f16 Ash[128 * 64];
  __shared__ f16 Bsh[128 * 64];
  int b = blockIdx.x;
  int g = (b & 7) * per + (b >> 3);
  if (g >= mt * nt) return;
  int tm = (g / nt) * 128, tn = (g % nt) * 128;

  int tid = threadIdx.x;
  int l = tid & 63, w = tid >> 6;

  // staging: 4 A-loads + 4 B-loads per thread per K-iter (8 rows x 128B each)
  const f16* ag[4]; const f16* bg[4];
  uint32_t lof[4];
  #pragma unroll
  for (int j = 0; j < 4; ++j) {
    int rl = w * 32 + j * 8 + (l >> 3);       // local row
    int ck = l & 7;                           // physical 16B chunk slot
    int lc = ck ^ (rl & 7);                   // logical chunk fetched (XOR swizzle)
    int gr = tm + rl; if (gr > M - 1) gr = M - 1;
    int gn = tn + rl; if (gn > N - 1) gn = N - 1;
    ag[j] = A + (size_t)gr * lda + lc * 8;
    bg[j] = Bt + (size_t)gn * K + lc * 8;
    lof[j] = (uint32_t)(w * 32 + j * 8) * 128; // wave-uniform LDS byte base
  }

  // fragment LDS pointers: logical chunk (kk*4+q) of row m at phys (kk*4+q)^(m&7)
  int wm = (w >> 1) * 64, wn = (w & 1) * 64;
  int q = l >> 4, l15 = l & 15;
  const f16x8* apf[4][2]; const f16x8* bpf[4][2];
  #pragma unroll
  for (int i = 0; i < 4; ++i) {
    int m = wm + i * 16 + l15;
    int n2 = wn + i * 16 + l15;
    #pragma unroll
    for (int kk = 0; kk < 2; ++kk) {
      apf[i][kk] = (const f16x8*)&Ash[m * 64 + (((kk << 2) | q) ^ (m & 7)) * 8];
      bpf[i][kk] = (const f16x8*)&Bsh[n2 * 64 + (((kk << 2) | q) ^ (n2 & 7)) * 8];
    }
  }

  floatx4 acc[4][4];
  #pragma unroll
  for (int i = 0; i < 4; ++i)
    #pragma unroll
    for (int j = 0; j < 4; ++j) acc[i][j] = (floatx4){0.f, 0.f, 0.f, 0.f};

  for (int k0 = 0; k0 < K; k0 += 64) {
    if (k0) __syncthreads();
    #pragma unroll
    for (int j = 0; j < 4; ++j) {
      __builtin_amdgcn_global_load_lds(
          (const __attribute__((address_space(1))) void*)ag[j],
          (__attribute__((address_space(3))) void*)((char*)Ash + lof[j]), 16, 0, 0);
      __builtin_amdgcn_global_load_lds(
          (const __attribute__((address_space(1))) void*)bg[j],
          (__attribute__((address_space(3))) void*)((char*)Bsh + lof[j]), 16, 0, 0);
      ag[j] += 64; bg[j] += 64;
    }
    __syncthreads();  // drains vmcnt(0): LDS-DMA visible
    #pragma unroll
    for (int kk = 0; kk < 2; ++kk) {
      f16x8 af[4], bf[4];
      #pragma unroll
      for (int i = 0; i < 4; ++i) { af[i] = *apf[i][kk]; bf[i] = *bpf[i][kk]; }
      #pragma unroll
      for (int mi = 0; mi < 4; ++mi)
        #pragma unroll
        for (int ni = 0; ni < 4; ++ni)
          acc[mi][ni] = __builtin_amdgcn_mfma_f32_16x16x32_f16(af[mi], bf[ni], acc[mi][ni], 0, 0, 0);
    }
  }

  // epilogue: C/D layout col=lane&15, row=quad*4+reg (m89-verified)
  #pragma unroll
  for (int ni = 0; ni < 4; ++ni) {
    int col = tn + wn + ni * 16 + l15;
    if (col >= N) continue;
    float bv = bias ? bias[col] : 0.f;
    #pragma unroll
    for (int mi = 0; mi < 4; ++mi) {
      int rowb = tm + wm + mi * 16 + q * 4;
      #pragma unroll
      for (int r = 0; r < 4; ++r) {
        int row = rowb + r;
        if (row < M) {
          float v = acc[mi][ni][r] + bv;
          if (relu) v = fmaxf(v, 0.f);
          if (outf) ((float*)Cv)[(size_t)row * ldc + col] = v;
          else      ((f16*)Cv)[(size_t)row * ldc + col] = (f16)v;
        }
      }
    }
  }
}

// ---------------------------------------------------------------------------
// host orchestration
// ---------------------------------------------------------------------------
extern "C" void kernel_launch(void* const* d_in, const int* in_sizes, int n_in,
                              void* d_out, int out_size, void* d_ws, size_t ws_size,
                              hipStream_t stream) {
  (void)in_sizes; (void)n_in; (void)out_size; (void)ws_size;
  const int NL = 50000, NJ = 25000, EL = 400000, EJ = 100000;

  const float* x_l  = (const float*)d_in[0];
  const float* x_j  = (const float*)d_in[1];
  const int*   ei_l = (const int*)d_in[2];
  const int*   ei_j = (const int*)d_in[3];
  const float* lgW1 = (const float*)d_in[4];  const float* lgb1 = (const float*)d_in[5];
  const float* lgg1 = (const float*)d_in[6];  const float* lgbe1= (const float*)d_in[7];
  const float* lgW2 = (const float*)d_in[8];  const float* lgb2 = (const float*)d_in[9];
  const float* lgg2 = (const float*)d_in[10]; const float* lgbe2= (const float*)d_in[11];
  const float* lgfcW= (const float*)d_in[12]; const float* lgfcb= (const float*)d_in[13];
  const float* flW1 = (const float*)d_in[14]; const float* flb1 = (const float*)d_in[15];
  const float* flW2 = (const float*)d_in[16]; const float* flb2 = (const float*)d_in[17];
  const float* flW3 = (const float*)d_in[18]; const float* flb3 = (const float*)d_in[19];
  const float* jgW1 = (const float*)d_in[20]; const float* jgb1 = (const float*)d_in[21];
  const float* jgg1 = (const float*)d_in[22]; const float* jgbe1= (const float*)d_in[23];
  const float* jgW2 = (const float*)d_in[24]; const float* jgb2 = (const float*)d_in[25];
  const float* jgg2 = (const float*)d_in[26]; const float* jgbe2= (const float*)d_in[27];
  const float* jgfcW= (const float*)d_in[28]; const float* jgfcb= (const float*)d_in[29];
  const float* fjW1 = (const float*)d_in[30]; const float* fjb1 = (const float*)d_in[31];
  const float* fjW2 = (const float*)d_in[32]; const float* fjb2 = (const float*)d_in[33];

  char* ws = (char*)d_ws;
  size_t off = 0;
  auto alloc = [&](size_t bytes) -> char* {
    char* p = ws + off;
    off += (bytes + 255) & ~(size_t)255;
    return p;
  };

  f16* cat16 = (f16*)alloc((size_t)NL * 1792 * 2);   // [x | h1 | h2]
  f16* hA    = (f16*)alloc((size_t)NL * 1024 * 2);
  f16* hB    = (f16*)alloc((size_t)NL * 1024 * 2);
  float* vbuf = (float*)hA;   // alias: GCN phase only
  f16*  xw16  = (f16*)hB;
  f16* catJ  = (f16*)alloc((size_t)NJ * 448 * 2);
  f16* hJA   = (f16*)alloc((size_t)NJ * 256 * 2);
  f16* hJB   = (f16*)alloc((size_t)NJ * 64 * 2);
  float* vbufJ = (float*)hA;  // junction branch runs after line branch
  f16*  xwJ   = (f16*)hB;

  f16* W1t   = (f16*)alloc((size_t)1024 * 512 * 2);
  f16* W2t   = (f16*)alloc((size_t)512 * 256 * 2);
  f16* fcWt  = (f16*)alloc((size_t)1792 * 1024 * 2);
  f16* flW1t = (f16*)alloc((size_t)1024 * 1024 * 2);
  f16* flW2t = (f16*)alloc((size_t)1024 * 1024 * 2);
  f16* flW3t = (f16*)alloc((size_t)1024 * 16 * 2);
  f16* jW1t  = (f16*)alloc((size_t)256 * 128 * 2);
  f16* jW2t  = (f16*)alloc((size_t)128 * 64 * 2);
  f16* jfcWt = (f16*)alloc((size_t)448 * 256 * 2);
  f16* fjW1t = (f16*)alloc((size_t)256 * 64 * 2);
  f16* fjW2t = (f16*)alloc((size_t)64 * 4 * 2);

  int* cntL  = (int*)alloc((size_t)2 * NL * 4);      // [cnt | fill] combined
  int* fillL = cntL + NL;
  int* rsL   = (int*)alloc((size_t)(NL + 1) * 4);
  int* cixL  = (int*)alloc((size_t)EL * 4);
  float* disL= (float*)alloc((size_t)NL * 4);
  int* cntJ  = (int*)alloc((size_t)2 * NJ * 4);
  int* fillJ = cntJ + NJ;
  int* rsJ   = (int*)alloc((size_t)(NJ + 1) * 4);
  int* cixJ  = (int*)alloc((size_t)EJ * 4);
  float* disJ= (float*)alloc((size_t)NJ * 4);
  float* sumc  = (float*)alloc(2 * 512 * 4);         // [sum | sumsq] combined
  float* sumqc = sumc + 512;
  float* scalc = (float*)alloc(512 * 4);
  float* shftc = (float*)alloc(512 * 4);

  auto cdiv = [](int a, int b) { return (a + b - 1) / b; };

  auto gemm = [&](const f16* A, int lda, const f16* Bt, void* Cc, int ldc,
                  const float* bias, int relu, int outf, int M, int N, int K) {
    int mt = cdiv(M, 128), nt = cdiv(N, 128);
    int per = cdiv(mt * nt, 8);
    k_gemm<<<8 * per, 256, 0, stream>>>(A, lda, Bt, Cc, ldc, bias, relu, outf,
                                        M, N, K, mt, nt, per);
  };
  auto csr = [&](const int* ei, int E, int n, int* cnt, int* rs, int* fill,
                 int* cix, float* dis) {
    hipMemsetAsync(cnt, 0, (size_t)2 * n * 4, stream);  // cnt + fill
    k_count<<<cdiv(E, 256), 256, 0, stream>>>(ei + E, E, cnt);
    k_scan<<<1, 1024, 0, stream>>>(cnt, n, rs, dis);
    k_fill<<<cdiv(E, 256), 256, 0, stream>>>(ei, E, rs, fill, cix);
  };
  auto bn = [&](float* v, int n, int C, const float* gamma, const float* beta,
                f16* dst, int ldd, int coff) {
    hipMemsetAsync(sumc, 0, (size_t)2 * 512 * 4, stream);
    dim3 gs(cdiv(C, 256), cdiv(n, 128));
    k_stats<<<gs, 256, 0, stream>>>(v, n, C, sumc, sumqc);
    k_bnparam<<<cdiv(C, 256), 256, 0, stream>>>(sumc, sumqc, gamma, beta, n, C, scalc, shftc);
    k_bnapply<<<cdiv(n * (C >> 2), 256), 256, 0, stream>>>(v, n, C, scalc, shftc, dst, ldd, coff);
  };

  // ---- all weight transpose-converts in ONE launch ----
  {
    WtBatch B2; int base = 0, nj = 0;
    auto add = [&](const float* W, f16* Wt, int K, int N) {
      B2.j[nj++] = WtJob{W, Wt, K, N, base};
      base += K * N;
    };
    add(lgW1, W1t, 1024, 512);
    add(lgW2, W2t, 512, 256);
    add(lgfcW, fcWt, 1792, 1024);
    add(flW1, flW1t, 1024, 1024);
    add(flW2, flW2t, 1024, 1024);
    add(flW3, flW3t, 1024, 10);
    add(jgW1, jW1t, 256, 128);
    add(jgW2, jW2t, 128, 64);
    add(jgfcW, jfcWt, 448, 256);
    add(fjW1, fjW1t, 256, 64);
    add(fjW2, fjW2t, 64, 3);
    B2.njobs = nj; B2.total = base;
    k_wt_all<<<cdiv(base, 256), 256, 0, stream>>>(B2);
  }

  // ---- feature conversion into concat buffers ----
  k_cvt_cols<<<cdiv(NL * 256, 256), 256, 0, stream>>>(x_l, cat16, NL, 1024, 1792, 0);
  k_cvt_cols<<<cdiv(NJ * 64, 256), 256, 0, stream>>>(x_j, catJ, NJ, 256, 448, 0);

  // ================= line branch =================
  csr(ei_l, EL, NL, cntL, rsL, fillL, cixL, disL);

  // GCN layer 1: 1024 -> 512
  gemm(cat16, 1792, W1t, xw16, 512, nullptr, 0, 0, NL, 512, 1024);
  k_gather_v<8><<<cdiv(NL, 4), 256, 0, stream>>>(xw16, 512, rsL, cixL, disL, lgb1, vbuf, NL);
  bn(vbuf, NL, 512, lgg1, lgbe1, cat16, 1792, 1024);

  // GCN layer 2: 512 -> 256
  gemm(cat16 + 1024, 1792, W2t, xw16, 256, nullptr, 0, 0, NL, 256, 512);
  k_gather_v<4><<<cdiv(NL, 4), 256, 0, stream>>>(xw16, 256, rsL, cixL, disL, lgb2, vbuf, NL);
  bn(vbuf, NL, 256, lgg2, lgbe2, cat16, 1792, 1536);

  // fc over concat(1792) + fl stack + final logits (fp32 out, MFMA)
  gemm(cat16, 1792, fcWt, hA, 1024, lgfcb, 1, 0, NL, 1024, 1792);
  gemm(hA, 1024, flW1t, hB, 1024, flb1, 1, 0, NL, 1024, 1024);
  gemm(hB, 1024, flW2t, hA, 1024, flb2, 1, 0, NL, 1024, 1024);
  gemm(hA, 1024, flW3t, (float*)d_out, 10, flb3, 0, 1, NL, 10, 1024);

  // ================= junction branch =================
  csr(ei_j, EJ, NJ, cntJ, rsJ, fillJ, cixJ, disJ);

  gemm(catJ, 448, jW1t, xwJ, 128, nullptr, 0, 0, NJ, 128, 256);
  k_gather_v<2><<<cdiv(NJ, 4), 256, 0, stream>>>(xwJ, 128, rsJ, cixJ, disJ, jgb1, vbufJ, NJ);
  bn(vbufJ, NJ, 128, jgg1, jgbe1, catJ, 448, 256);

  gemm(catJ + 256, 448, jW2t, xwJ, 64, nullptr, 0, 0, NJ, 64, 128);
  k_gather_v<1><<<cdiv(NJ, 4), 256, 0, stream>>>(xwJ, 64, rsJ, cixJ, disJ, jgb2, vbufJ, NJ);
  bn(vbufJ, NJ, 64, jgg2, jgbe2, catJ, 448, 384);

  gemm(catJ, 448, jfcWt, hJA, 256, jgfcb, 1, 0, NJ, 256, 448);
  gemm(hJA, 256, fjW1t, hJB, 64, fjb1, 1, 0, NJ, 64, 256);
  gemm(hJB, 64, fjW2t, (float*)d_out + (size_t)NL * 10, 3, fjb2, 0, 1, NJ, 3, 64);
}

// Round 3
// 1726.606 us; speedup vs baseline: 1.3313x; 1.0128x over previous
//
#include <hip/hip_runtime.h>
#include <stdint.h>
#include <stddef.h>

typedef _Float16 f16;
typedef _Float16 f16x8 __attribute__((ext_vector_type(8)));
typedef _Float16 f16x4_t __attribute__((ext_vector_type(4)));
typedef float floatx4 __attribute__((ext_vector_type(4)));

template <int N> struct F16Vec { typedef f16 type __attribute__((ext_vector_type(N))); };

#define BN_EPS 1e-5f

// ---------------------------------------------------------------------------
// batched LDS-tiled weight transpose-convert: W [K,N] fp32 -> Wt [N,K] fp16
// ---------------------------------------------------------------------------
struct WtJob { const float* W; f16* Wt; int K; int N; int tN; int tilebase; };
struct WtBatch { WtJob j[12]; int njobs; int ntiles; };

__global__ void k_wt_tiled(WtBatch b) {
  __shared__ float T[32][33];
  int bt = blockIdx.x;
  int i = 0;
  #pragma unroll 1
  while (i + 1 < b.njobs && bt >= b.j[i + 1].tilebase) ++i;
  WtJob J = b.j[i];
  int t = bt - J.tilebase;
  int tr = t / J.tN, tc = t - tr * J.tN;      // K-tile, N-tile
  int ty = threadIdx.x >> 5, tx = threadIdx.x & 31;
  #pragma unroll
  for (int s = 0; s < 32; s += 8) {
    int k = tr * 32 + ty + s, n = tc * 32 + tx;
    if (k < J.K && n < J.N) T[ty + s][tx] = J.W[(size_t)k * J.N + n];
  }
  __syncthreads();
  #pragma unroll
  for (int s = 0; s < 32; s += 8) {
    int n = tc * 32 + ty + s, k = tr * 32 + tx;
    if (n < J.N && k < J.K) J.Wt[(size_t)n * J.K + k] = (f16)T[tx][ty + s];
  }
}

// fp32 [n,c] -> fp16 into dst[r*ldd + coff + j]  (c % 4 == 0)
__global__ void k_cvt_cols(const float* __restrict__ src, f16* __restrict__ dst,
                           int n, int c, int ldd, int coff) {
  int t = blockIdx.x * blockDim.x + threadIdx.x;
  int cq = c >> 2;
  if (t >= n * cq) return;
  int r = t / cq, j = (t - r * cq) << 2;
  float4 v = *(const float4*)(src + (size_t)r * c + j);
  f16x4_t o; o[0] = (f16)v.x; o[1] = (f16)v.y; o[2] = (f16)v.z; o[3] = (f16)v.w;
  *(f16x4_t*)(dst + (size_t)r * ldd + coff + j) = o;
}

// ---------------------------------------------------------------------------
// CSR build (both graphs fused where possible)
// ---------------------------------------------------------------------------
__global__ void k_count2(const int* __restrict__ dL, int EL, int* __restrict__ cntL,
                         const int* __restrict__ dJ, int EJ, int* __restrict__ cntJ) {
  int t = blockIdx.x * blockDim.x + threadIdx.x;
  if (t < EL) atomicAdd(&cntL[dL[t]], 1);
  else if (t < EL + EJ) atomicAdd(&cntJ[dJ[t - EL]], 1);
}

// 1024 threads, 4 elems/thread/strip; n % 4 == 0
__global__ void k_scan4(const int* __restrict__ cnt, int n, int* __restrict__ rowstart,
                        float* __restrict__ dis) {
  __shared__ int wsum[16];
  __shared__ int carry_s;
  int tid = threadIdx.x, lane = tid & 63, wv = tid >> 6;
  if (tid == 0) { carry_s = 0; rowstart[0] = 0; }
  __syncthreads();
  for (int base = 0; base < n; base += 4096) {
    int i4 = base + tid * 4;
    int4 c = {0, 0, 0, 0};
    if (i4 < n) c = *(const int4*)(cnt + i4);
    int s0 = c.x, s1 = s0 + c.y, s2 = s1 + c.z, s3 = s2 + c.w;
    int x = s3;
    #pragma unroll
    for (int off = 1; off < 64; off <<= 1) {
      int y = __shfl_up(x, off, 64);
      if (lane >= off) x += y;
    }
    if (lane == 63) wsum[wv] = x;
    __syncthreads();
    if (wv == 0) {
      int s = (lane < 16) ? wsum[lane] : 0;
      #pragma unroll
      for (int off = 1; off < 16; off <<= 1) {
        int y = __shfl_up(s, off, 64);
        if (lane >= off) s += y;
      }
      if (lane < 16) wsum[lane] = s;
    }
    __syncthreads();
    int waveoff = (wv == 0) ? 0 : wsum[wv - 1];
    int excl = (x - s3) + waveoff + carry_s;   // exclusive prefix for this thread
    if (i4 < n) {
      rowstart[i4 + 1] = excl + s0;
      rowstart[i4 + 2] = excl + s1;
      rowstart[i4 + 3] = excl + s2;
      rowstart[i4 + 4] = excl + s3;
      dis[i4 + 0] = rsqrtf(1.0f + (float)c.x);
      dis[i4 + 1] = rsqrtf(1.0f + (float)c.y);
      dis[i4 + 2] = rsqrtf(1.0f + (float)c.z);
      dis[i4 + 3] = rsqrtf(1.0f + (float)c.w);
    }
    __syncthreads();
    if (tid == 1023) carry_s = excl + s3;
    __syncthreads();
  }
}

__global__ void k_fill2(const int* __restrict__ eiL, int EL, const int* __restrict__ rsL,
                        int* __restrict__ fillL, int* __restrict__ cixL,
                        const int* __restrict__ eiJ, int EJ, const int* __restrict__ rsJ,
                        int* __restrict__ fillJ, int* __restrict__ cixJ) {
  int t = blockIdx.x * blockDim.x + threadIdx.x;
  if (t < EL) {
    int s = eiL[t], d = eiL[EL + t];
    int pos = atomicAdd(&fillL[d], 1);
    cixL[rsL[d] + pos] = s;
  } else if (t < EL + EJ) {
    int u = t - EL;
    int s = eiJ[u], d = eiJ[EJ + u];
    int pos = atomicAdd(&fillJ[d], 1);
    cixJ[rsJ[d] + pos] = s;
  }
}

// ---------------------------------------------------------------------------
// GCN aggregation: one WAVE per node, CPL channels/lane, writes f16 into the
// concat slice (bias folded). acc fp32.
// ---------------------------------------------------------------------------
template <int CPL>
__global__ void k_gather_f16(const f16* __restrict__ xw, int C,
                             const int* __restrict__ rowstart, const int* __restrict__ colidx,
                             const float* __restrict__ dis, const float* __restrict__ bias,
                             f16* __restrict__ dst, int ldd, int coff, int n) {
  typedef typename F16Vec<CPL>::type V;
  int w = threadIdx.x >> 6, l = threadIdx.x & 63;
  int j = blockIdx.x * 4 + w;
  if (j >= n) return;
  float dj = dis[j];
  int rs = rowstart[j], re = rowstart[j + 1];
  int c0 = l * CPL;
  float acc[CPL];
  {
    V p = *(const V*)(xw + (size_t)j * C + c0);
    float s = dj * dj;
    #pragma unroll
    for (int t = 0; t < CPL; ++t) acc[t] = (float)p[t] * s;
  }
  int e = rs;
  for (; e + 2 <= re; e += 2) {
    int s0 = colidx[e], s1 = colidx[e + 1];
    float f0 = dis[s0] * dj, f1 = dis[s1] * dj;
    V p0 = *(const V*)(xw + (size_t)s0 * C + c0);
    V p1 = *(const V*)(xw + (size_t)s1 * C + c0);
    #pragma unroll
    for (int t = 0; t < CPL; ++t) acc[t] += (float)p0[t] * f0 + (float)p1[t] * f1;
  }
  if (e < re) {
    int s0 = colidx[e];
    float f0 = dis[s0] * dj;
    V p0 = *(const V*)(xw + (size_t)s0 * C + c0);
    #pragma unroll
    for (int t = 0; t < CPL; ++t) acc[t] += (float)p0[t] * f0;
  }
  V o;
  #pragma unroll
  for (int t = 0; t < CPL; ++t) o[t] = (f16)(acc[t] + bias[c0 + t]);
  *(V*)(dst + (size_t)j * ldd + coff + c0) = o;
}

// ---------------------------------------------------------------------------
// BatchNorm over f16 slice: stats -> params -> apply(+relu) in place
// ---------------------------------------------------------------------------
__global__ void k_stats(const f16* __restrict__ v, int ldd, int coff, int n, int C,
                        float* __restrict__ sum, float* __restrict__ sumsq) {
  int c = blockIdx.x * blockDim.x + threadIdx.x;
  if (c >= C) return;
  int r0 = blockIdx.y * 128, r1 = min(r0 + 128, n);
  float s = 0.f, s2 = 0.f;
  for (int r = r0; r < r1; ++r) {
    float x = (float)v[(size_t)r * ldd + coff + c];
    s += x; s2 += x * x;
  }
  atomicAdd(&sum[c], s);
  atomicAdd(&sumsq[c], s2);
}

__global__ void k_bnparam(const float* __restrict__ sum, const float* __restrict__ sumsq,
                          const float* __restrict__ gamma, const float* __restrict__ beta,
                          int n, int C, float* __restrict__ scale, float* __restrict__ shift) {
  int c = blockIdx.x * blockDim.x + threadIdx.x;
  if (c >= C) return;
  float mean = sum[c] / (float)n;
  float var = sumsq[c] / (float)n - mean * mean;
  float sc = gamma[c] * rsqrtf(var + BN_EPS);
  scale[c] = sc;
  shift[c] = beta[c] - mean * sc;
}

__global__ void k_bnapply_ip(f16* __restrict__ v, int ldd, int coff, int n, int C,
                             const float* __restrict__ scale, const float* __restrict__ shift) {
  int t = blockIdx.x * blockDim.x + threadIdx.x;
  int cq = C >> 2;
  if (t >= n * cq) return;
  int r = t / cq, c = (t - r * cq) << 2;
  f16* p = v + (size_t)r * ldd + coff + c;
  f16x4_t x = *(f16x4_t*)p;
  float4 sc = *(const float4*)(scale + c);
  float4 sh = *(const float4*)(shift + c);
  f16x4_t o;
  o[0] = (f16)fmaxf((float)x[0] * sc.x + sh.x, 0.f);
  o[1] = (f16)fmaxf((float)x[1] * sc.y + sh.y, 0.f);
  o[2] = (f16)fmaxf((float)x[2] * sc.z + sh.z, 0.f);
  o[3] = (f16)fmaxf((float)x[3] * sc.w + sh.w, 0.f);
  *(f16x4_t*)p = o;
}

// ---------------------------------------------------------------------------
// fp16 MFMA GEMM: C[M,N] = A[M,K] @ Bt[N,K]^T  (+bias, +relu), f16 or f32 out.
// 128x128 tile, 4 waves (2x2 of 64x64), 16x16x32 f16 MFMA, BK=32,
// DOUBLE-BUFFERED global_load_lds (prefetch dist 1, ONE barrier per iter):
// barrier waits on loads issued a full MFMA-block earlier -> latency hidden.
// XOR chunk swizzle (2-way bank alias = free), XCD-aware 1D block swizzle.
// ---------------------------------------------------------------------------
__global__ __launch_bounds__(256)
void k_gemm(const f16* __restrict__ A, int lda,
            const f16* __restrict__ Bt,
            void* __restrict__ Cv, int ldc,
            const float* __restrict__ bias, int relu, int outf,
            int M, int N, int K, int mt, int nt, int per) {
  __shared__ f16 Ash[2][128 * 32];   // 2 x 8 KB
  __shared__ f16 Bsh[2][128 * 32];
  int b = blockIdx.x;
  int g = (b & 7) * per + (b >> 3);
  if (g >= mt * nt) return;
  int tm = (g / nt) * 128, tn = (g % nt) * 128;
  int tid = threadIdx.x, l = tid & 63, w = tid >> 6;

  // staging: 2 A-loads + 2 B-loads per thread per K-iter (16 rows x 64 B each)
  const f16* ag[2]; const f16* bg[2];
  uint32_t lof[2];
  #pragma unroll
  for (int j = 0; j < 2; ++j) {
    int rl = w * 32 + j * 16 + (l >> 2);
    int ck = l & 3;                      // physical 16B slot (DMA: lane*16)
    int lc = ck ^ ((rl >> 1) & 3);       // logical chunk fetched (XOR swizzle)
    int gr = tm + rl; if (gr > M - 1) gr = M - 1;
    int gn = tn + rl; if (gn > N - 1) gn = N - 1;
    ag[j] = A + (size_t)gr * lda + lc * 8;
    bg[j] = Bt + (size_t)gn * K + lc * 8;
    lof[j] = (uint32_t)(w * 32 + j * 16) * 64;  // wave-uniform LDS byte base
  }

  // fragment byte offsets within one buffer
  int wm = (w >> 1) * 64, wn = (w & 1) * 64;
  int q = l >> 4, l15 = l & 15;
  uint32_t aoffb[4], boffb[4];
  #pragma unroll
  for (int i = 0; i < 4; ++i) {
    int m = wm + i * 16 + l15;
    int n2 = wn + i * 16 + l15;
    aoffb[i] = (uint32_t)(m * 32 + (q ^ ((m >> 1) & 3)) * 8) * 2;
    boffb[i] = (uint32_t)(n2 * 32 + (q ^ ((n2 >> 1) & 3)) * 8) * 2;
  }

  floatx4 acc[4][4];
  #pragma unroll
  for (int i = 0; i < 4; ++i)
    #pragma unroll
    for (int j = 0; j < 4; ++j) acc[i][j] = (floatx4){0.f, 0.f, 0.f, 0.f};

  int nk = K >> 5;
  // prologue: tile 0 -> buf 0
  #pragma unroll
  for (int j = 0; j < 2; ++j) {
    __builtin_amdgcn_global_load_lds(
        (const __attribute__((address_space(1))) void*)ag[j],
        (__attribute__((address_space(3))) void*)((char*)Ash + lof[j]), 16, 0, 0);
    __builtin_amdgcn_global_load_lds(
        (const __attribute__((address_space(1))) void*)bg[j],
        (__attribute__((address_space(3))) void*)((char*)Bsh + lof[j]), 16, 0, 0);
    ag[j] += 32; bg[j] += 32;
  }

  for (int i = 0; i < nk; ++i) {
    __syncthreads();  // vmcnt(0): buf[i&1] DMA done; lgkm: prior reads consumed
    if (i + 1 < nk) {
      uint32_t d = ((i + 1) & 1) ? 8192u : 0u;
      #pragma unroll
      for (int j = 0; j < 2; ++j) {
        __builtin_amdgcn_global_load_lds(
            (const __attribute__((address_space(1))) void*)ag[j],
            (__attribute__((address_space(3))) void*)((char*)Ash + d + lof[j]), 16, 0, 0);
        __builtin_amdgcn_global_load_lds(
            (const __attribute__((address_space(1))) void*)bg[j],
            (__attribute__((address_space(3))) void*)((char*)Bsh + d + lof[j]), 16, 0, 0);
        ag[j] += 32; bg[j] += 32;
      }
    }
    uint32_t s = (i & 1) ? 8192u : 0u;
    f16x8 af[4], bf[4];
    #pragma unroll
    for (int ii = 0; ii < 4; ++ii) {
      af[ii] = *(const f16x8*)((const char*)Ash + s + aoffb[ii]);
      bf[ii] = *(const f16x8*)((const char*)Bsh + s + boffb[ii]);
    }
    #pragma unroll
    for (int mi = 0; mi < 4; ++mi)
      #pragma unroll
      for (int ni = 0; ni < 4; ++ni)
        acc[mi][ni] = __builtin_amdgcn_mfma_f32_16x16x32_f16(af[mi], bf[ni], acc[mi][ni], 0, 0, 0);
  }

  // epilogue: C/D layout col=lane&15, row=quad*4+reg (m89-verified)
  #pragma unroll
  for (int ni = 0; ni < 4; ++ni) {
    int col = tn + wn + ni * 16 + l15;
    if (col >= N) continue;
    float bv = bias ? bias[col] : 0.f;
    #pragma unroll
    for (int mi = 0; mi < 4; ++mi) {
      int rowb = tm + wm + mi * 16 + q * 4;
      #pragma unroll
      for (int r = 0; r < 4; ++r) {
        int row = rowb + r;
        if (row < M) {
          float v = acc[mi][ni][r] + bv;
          if (relu) v = fmaxf(v, 0.f);
          if (outf) ((float*)Cv)[(size_t)row * ldc + col] = v;
          else      ((f16*)Cv)[(size_t)row * ldc + col] = (f16)v;
        }
      }
    }
  }
}

// ---------------------------------------------------------------------------
// host orchestration
// ---------------------------------------------------------------------------
extern "C" void kernel_launch(void* const* d_in, const int* in_sizes, int n_in,
                              void* d_out, int out_size, void* d_ws, size_t ws_size,
                              hipStream_t stream) {
  (void)in_sizes; (void)n_in; (void)out_size; (void)ws_size;
  const int NL = 50000, NJ = 25000, EL = 400000, EJ = 100000;

  const float* x_l  = (const float*)d_in[0];
  const float* x_j  = (const float*)d_in[1];
  const int*   ei_l = (const int*)d_in[2];
  const int*   ei_j = (const int*)d_in[3];
  const float* lgW1 = (const float*)d_in[4];  const float* lgb1 = (const float*)d_in[5];
  const float* lgg1 = (const float*)d_in[6];  const float* lgbe1= (const float*)d_in[7];
  const float* lgW2 = (const float*)d_in[8];  const float* lgb2 = (const float*)d_in[9];
  const float* lgg2 = (const float*)d_in[10]; const float* lgbe2= (const float*)d_in[11];
  const float* lgfcW= (const float*)d_in[12]; const float* lgfcb= (const float*)d_in[13];
  const float* flW1 = (const float*)d_in[14]; const float* flb1 = (const float*)d_in[15];
  const float* flW2 = (const float*)d_in[16]; const float* flb2 = (const float*)d_in[17];
  const float* flW3 = (const float*)d_in[18]; const float* flb3 = (const float*)d_in[19];
  const float* jgW1 = (const float*)d_in[20]; const float* jgb1 = (const float*)d_in[21];
  const float* jgg1 = (const float*)d_in[22]; const float* jgbe1= (const float*)d_in[23];
  const float* jgW2 = (const float*)d_in[24]; const float* jgb2 = (const float*)d_in[25];
  const float* jgg2 = (const float*)d_in[26]; const float* jgbe2= (const float*)d_in[27];
  const float* jgfcW= (const float*)d_in[28]; const float* jgfcb= (const float*)d_in[29];
  const float* fjW1 = (const float*)d_in[30]; const float* fjb1 = (const float*)d_in[31];
  const float* fjW2 = (const float*)d_in[32]; const float* fjb2 = (const float*)d_in[33];

  char* ws = (char*)d_ws;
  size_t off = 0;
  auto alloc = [&](size_t bytes) -> char* {
    char* p = ws + off;
    off += (bytes + 255) & ~(size_t)255;
    return p;
  };

  f16* cat16 = (f16*)alloc((size_t)NL * 1792 * 2);   // [x | h1 | h2]
  f16* hA    = (f16*)alloc((size_t)NL * 1024 * 2);
  f16* hB    = (f16*)alloc((size_t)NL * 1024 * 2);
  f16*  xw16  = (f16*)hB;      // alias: GCN phase only (hB first written at fl1)
  f16* catJ  = (f16*)alloc((size_t)NJ * 448 * 2);
  f16* hJA   = (f16*)alloc((size_t)NJ * 256 * 2);
  f16* hJB   = (f16*)alloc((size_t)NJ * 64 * 2);
  f16*  xwJ   = (f16*)hB;      // junction branch runs after line branch

  f16* W1t   = (f16*)alloc((size_t)1024 * 512 * 2);
  f16* W2t   = (f16*)alloc((size_t)512 * 256 * 2);
  f16* fcWt  = (f16*)alloc((size_t)1792 * 1024 * 2);
  f16* flW1t = (f16*)alloc((size_t)1024 * 1024 * 2);
  f16* flW2t = (f16*)alloc((size_t)1024 * 1024 * 2);
  f16* flW3t = (f16*)alloc((size_t)1024 * 16 * 2);
  f16* jW1t  = (f16*)alloc((size_t)256 * 128 * 2);
  f16* jW2t  = (f16*)alloc((size_t)128 * 64 * 2);
  f16* jfcWt = (f16*)alloc((size_t)448 * 256 * 2);
  f16* fjW1t = (f16*)alloc((size_t)256 * 64 * 2);
  f16* fjW2t = (f16*)alloc((size_t)64 * 4 * 2);

  // zero-region: [cntL | fillL | cntJ | fillJ | stats(1920 f32)]
  int* zero0 = (int*)alloc(((size_t)2 * NL + 2 * NJ + 1920) * 4);
  int* cntL  = zero0;
  int* fillL = cntL + NL;
  int* cntJ  = fillL + NL;
  int* fillJ = cntJ + NJ;
  float* stats = (float*)(fillJ + NJ);
  float* sum1L = stats;        float* sq1L = stats + 512;    // C=512
  float* sum2L = stats + 1024; float* sq2L = stats + 1280;   // C=256
  float* sum1J = stats + 1536; float* sq1J = stats + 1664;   // C=128
  float* sum2J = stats + 1792; float* sq2J = stats + 1856;   // C=64

  int* rsL   = (int*)alloc((size_t)(NL + 4) * 4);
  int* cixL  = (int*)alloc((size_t)EL * 4);
  float* disL= (float*)alloc((size_t)NL * 4);
  int* rsJ   = (int*)alloc((size_t)(NJ + 4) * 4);
  int* cixJ  = (int*)alloc((size_t)EJ * 4);
  float* disJ= (float*)alloc((size_t)NJ * 4);
  float* scalc = (float*)alloc(512 * 4);
  float* shftc = (float*)alloc(512 * 4);

  auto cdiv = [](int a, int b) { return (a + b - 1) / b; };

  auto gemm = [&](const f16* A, int lda, const f16* Bt, void* Cc, int ldc,
                  const float* bias, int relu, int outf, int M, int N, int K) {
    int mt = cdiv(M, 128), nt = cdiv(N, 128);
    int per = cdiv(mt * nt, 8);
    k_gemm<<<8 * per, 256, 0, stream>>>(A, lda, Bt, Cc, ldc, bias, relu, outf,
                                        M, N, K, mt, nt, per);
  };
  auto bn = [&](f16* v, int ldd, int coff, int n, int C,
                float* sum, float* sumsq, const float* gamma, const float* beta) {
    dim3 gs(cdiv(C, 256), cdiv(n, 128));
    k_stats<<<gs, 256, 0, stream>>>(v, ldd, coff, n, C, sum, sumsq);
    k_bnparam<<<cdiv(C, 256), 256, 0, stream>>>(sum, sumsq, gamma, beta, n, C, scalc, shftc);
    k_bnapply_ip<<<cdiv(n * (C >> 2), 256), 256, 0, stream>>>(v, ldd, coff, n, C, scalc, shftc);
  };

  // ---- one memset for all zero-init scratch ----
  hipMemsetAsync(zero0, 0, ((size_t)2 * NL + 2 * NJ + 1920) * 4, stream);

  // ---- all weight transpose-converts in ONE tiled launch ----
  {
    WtBatch B2; int base = 0, nj = 0;
    auto add = [&](const float* W, f16* Wt, int K, int N) {
      int tK = cdiv(K, 32), tN = cdiv(N, 32);
      B2.j[nj++] = WtJob{W, Wt, K, N, tN, base};
      base += tK * tN;
    };
    add(lgW1, W1t, 1024, 512);
    add(lgW2, W2t, 512, 256);
    add(lgfcW, fcWt, 1792, 1024);
    add(flW1, flW1t, 1024, 1024);
    add(flW2, flW2t, 1024, 1024);
    add(flW3, flW3t, 1024, 10);
    add(jgW1, jW1t, 256, 128);
    add(jgW2, jW2t, 128, 64);
    add(jgfcW, jfcWt, 448, 256);
    add(fjW1, fjW1t, 256, 64);
    add(fjW2, fjW2t, 64, 3);
    B2.njobs = nj; B2.ntiles = base;
    k_wt_tiled<<<base, 256, 0, stream>>>(B2);
  }

  // ---- feature conversion into concat buffers ----
  k_cvt_cols<<<cdiv(NL * 256, 256), 256, 0, stream>>>(x_l, cat16, NL, 1024, 1792, 0);
  k_cvt_cols<<<cdiv(NJ * 64, 256), 256, 0, stream>>>(x_j, catJ, NJ, 256, 448, 0);

  // ---- CSR build for both graphs ----
  k_count2<<<cdiv(EL + EJ, 256), 256, 0, stream>>>(ei_l + EL, EL, cntL, ei_j + EJ, EJ, cntJ);
  k_scan4<<<1, 1024, 0, stream>>>(cntL, NL, rsL, disL);
  k_scan4<<<1, 1024, 0, stream>>>(cntJ, NJ, rsJ, disJ);
  k_fill2<<<cdiv(EL + EJ, 256), 256, 0, stream>>>(ei_l, EL, rsL, fillL, cixL,
                                                  ei_j, EJ, rsJ, fillJ, cixJ);

  // ================= line branch =================
  // GCN layer 1: 1024 -> 512
  gemm(cat16, 1792, W1t, xw16, 512, nullptr, 0, 0, NL, 512, 1024);
  k_gather_f16<8><<<cdiv(NL, 4), 256, 0, stream>>>(xw16, 512, rsL, cixL, disL, lgb1,
                                                   cat16, 1792, 1024, NL);
  bn(cat16, 1792, 1024, NL, 512, sum1L, sq1L, lgg1, lgbe1);

  // GCN layer 2: 512 -> 256
  gemm(cat16 + 1024, 1792, W2t, xw16, 256, nullptr, 0, 0, NL, 256, 512);
  k_gather_f16<4><<<cdiv(NL, 4), 256, 0, stream>>>(xw16, 256, rsL, cixL, disL, lgb2,
                                                   cat16, 1792, 1536, NL);
  bn(cat16, 1792, 1536, NL, 256, sum2L, sq2L, lgg2, lgbe2);

  // fc over concat(1792) + fl stack + final logits (fp32 out, MFMA)
  gemm(cat16, 1792, fcWt, hA, 1024, lgfcb, 1, 0, NL, 1024, 1792);
  gemm(hA, 1024, flW1t, hB, 1024, flb1, 1, 0, NL, 1024, 1024);
  gemm(hB, 1024, flW2t, hA, 1024, flb2, 1, 0, NL, 1024, 1024);
  gemm(hA, 1024, flW3t, (float*)d_out, 10, flb3, 0, 1, NL, 10, 1024);

  // ================= junction branch =================
  gemm(catJ, 448, jW1t, xwJ, 128, nullptr, 0, 0, NJ, 128, 256);
  k_gather_f16<2><<<cdiv(NJ, 4), 256, 0, stream>>>(xwJ, 128, rsJ, cixJ, disJ, jgb1,
                                                   catJ, 448, 256, NJ);
  bn(catJ, 448, 256, NJ, 128, sum1J, sq1J, jgg1, jgbe1);

  gemm(catJ + 256, 448, jW2t, xwJ, 64, nullptr, 0, 0, NJ, 64, 128);
  k_gather_f16<1><<<cdiv(NJ, 4), 256, 0, stream>>>(xwJ, 64, rsJ, cixJ, disJ, jgb2,
                                                   catJ, 448, 384, NJ);
  bn(catJ, 448, 384, NJ, 64, sum2J, sq2J, jgg2, jgbe2);

  gemm(catJ, 448, jfcWt, hJA, 256, jgfcb, 1, 0, NJ, 256, 448);
  gemm(hJA, 256, fjW1t, hJB, 64, fjb1, 1, 0, NJ, 64, 256);
  gemm(hJB, 64, fjW2t, (float*)d_out + (size_t)NL * 10, 3, fjb2, 0, 1, NJ, 3, 64);
}